// Round 2
// baseline (545.953 us; speedup 1.0000x reference)
//
#include <hip/hip_runtime.h>
#include <math.h>

namespace {
constexpr int Bb  = 8;
constexpr int Dd  = 384;
constexpr int HIN = 128;
constexpr int Cc  = 96;
constexpr int Nn  = 1024;
constexpr int NH  = 4;
constexpr int HD  = 24;
}
#define BN_EPS 1e-5f
#define QSCALE 0.20412414523193154f  /* 24^-0.5 */

typedef unsigned short u16;
typedef unsigned int   u32;
typedef __attribute__((ext_vector_type(8))) short bh8;   // 8 bf16 = 4 VGPR (MFMA A/B frag)
typedef __attribute__((ext_vector_type(4))) float fx4;   // MFMA C/D frag

#define MFMA16(a,b,c) __builtin_amdgcn_mfma_f32_16x16x32_bf16((a),(b),(c),0,0,0)

union PackU { u32 u[4]; bh8 s; };

// truncated hi/lo bf16 split: v == hi + lo to ~2^-16 relative
__device__ __forceinline__ void split1(float v, u16& hi, u16& lo) {
    const u32 bv = __float_as_uint(v);
    const u32 hb = bv & 0xffff0000u;
    hi = (u16)(bv >> 16);
    const float r = v - __uint_as_float(hb);   // exact (same exponent)
    lo = (u16)(__float_as_uint(r) >> 16);
}
// pack two floats into one dword of 2 bf16 (x->lo half, y->hi half) + residual pack
__device__ __forceinline__ void split2(float x, float y, u32& hi, u32& lo) {
    const u32 bx = __float_as_uint(x), by = __float_as_uint(y);
    const u32 hx = bx & 0xffff0000u, hy = by & 0xffff0000u;
    hi = (hx >> 16) | hy;
    const float rx = x - __uint_as_float(hx);
    const float ry = y - __uint_as_float(hy);
    lo = (__float_as_uint(rx) >> 16) | (__float_as_uint(ry) & 0xffff0000u);
}

__device__ __forceinline__ float bn_relu6(float y, const float* __restrict__ bn, int c) {
    float gam = bn[c], bet = bn[Cc + c], mu = bn[2*Cc + c], var = bn[3*Cc + c];
    float s = gam / sqrtf(var + BN_EPS);
    float r = (y - mu) * s + bet;
    return fminf(fmaxf(r, 0.0f), 6.0f);
}

// ---------------------------------------------------------------------------
// Stem: fused (grouped 4x4/s4 conv | 4x4 maxpool+grouped1x1 | 4x4 avgpool+grouped1x1)
// ---------------------------------------------------------------------------
__global__ __launch_bounds__(256) void stem_kernel(
    const float* __restrict__ x, const float* __restrict__ w_le,
    const float* __restrict__ b_le, const float* __restrict__ bn_le,
    const float* __restrict__ w_max, const float* __restrict__ b_max, const float* __restrict__ bn_max,
    const float* __restrict__ w_avg, const float* __restrict__ b_avg, const float* __restrict__ bn_avg,
    float* __restrict__ xq, float* __restrict__ tmx, float* __restrict__ tav)
{
    const int tid = threadIdx.x;
    const int n = blockIdx.x * 256 + tid;
    const int g = blockIdx.y;
    const int b = blockIdx.z;
    const int oh = n >> 5, ow = n & 31;

    const float* xb = x + (((size_t)b * Dd + 4*g) * HIN + 4*oh) * HIN + 4*ow;
    float conv = 0.0f, mxv = 0.0f, avv = 0.0f;
    #pragma unroll
    for (int i = 0; i < 4; ++i) {
        float cmax = -3.0e38f, csum = 0.0f;
        #pragma unroll
        for (int kh = 0; kh < 4; ++kh) {
            const float4 v = *(const float4*)(xb + ((size_t)i * HIN + kh) * HIN);
            const float* wl = w_le + (((g*4 + i)*4 + kh) * 4);
            conv = fmaf(v.x, wl[0], conv);
            conv = fmaf(v.y, wl[1], conv);
            conv = fmaf(v.z, wl[2], conv);
            conv = fmaf(v.w, wl[3], conv);
            cmax = fmaxf(cmax, fmaxf(fmaxf(v.x, v.y), fmaxf(v.z, v.w)));
            csum += (v.x + v.y) + (v.z + v.w);
        }
        mxv = fmaf(cmax, w_max[g*4 + i], mxv);
        avv = fmaf(csum * (1.0f/16.0f), w_avg[g*4 + i], avv);
    }
    const float xqv = bn_relu6(conv + b_le[g], bn_le, g);
    const float tm  = bn_relu6(mxv  + b_max[g], bn_max, g);
    const float ta  = bn_relu6(avv  + b_avg[g], bn_avg, g);
    const size_t o = ((size_t)b * Cc + g) * Nn + n;
    xq[o] = xqv; tmx[o] = tm; tav[o] = ta;
}

// ---------------------------------------------------------------------------
// Projections -> bf16 hi/lo MFMA operand layouts.
//   Q:  [bh][n][32]  (d pad 24..31 = 0; QSCALE pre-applied)
//   K:  [bh][rho(n)][32]  rows permuted within each 32-chunk:
//        row 32c+16t+4g+j holds key 32c+8g+4t+j  (so S^T C-frags line up with
//        the PV B-operand key slots with zero cross-lane traffic)
//   V^T:[bh][32][n]  (d rows 24..31 = 0)
// ---------------------------------------------------------------------------
__global__ __launch_bounds__(256) void proj_kernel(
    const float* __restrict__ xq, const float* __restrict__ tmx, const float* __restrict__ tav,
    const float* __restrict__ w_q, const float* __restrict__ w_kv,
    u16* __restrict__ qhp, u16* __restrict__ qlp,
    u16* __restrict__ k1h, u16* __restrict__ k1l, u16* __restrict__ k2h, u16* __restrict__ k2l,
    u16* __restrict__ v1h, u16* __restrict__ v1l, u16* __restrict__ v2h, u16* __restrict__ v2l)
{
    const int tid = threadIdx.x;
    const int n0 = blockIdx.x * 32;
    const int b  = blockIdx.y;
    __shared__ float axq[32*101];
    __shared__ float amx[32*101];
    __shared__ float aav[32*101];
    __shared__ float lw[96*97];

    for (int e = tid; e < 96*32; e += 256) {
        const int c = e >> 5, j = e & 31;
        const size_t src = ((size_t)b * Cc + c) * Nn + n0 + j;
        axq[j*101 + c] = xq[src];
        amx[j*101 + c] = tmx[src];
        aav[j*101 + c] = tav[src];
    }

    const int tn = (tid & 7) * 4;   // 4 rows (n)
    const int tc = (tid >> 3) * 3;  // 3 cols

    // ---- phase A: q ----
    __syncthreads();
    for (int e = tid; e < 96*96; e += 256) lw[(e/96)*97 + (e%96)] = w_q[e];
    __syncthreads();
    {
        float acc[4][3] = {};
        for (int k = 0; k < 96; ++k) {
            const float w0 = lw[k*97 + tc + 0];
            const float w1 = lw[k*97 + tc + 1];
            const float w2 = lw[k*97 + tc + 2];
            #pragma unroll
            for (int i = 0; i < 4; ++i) {
                const float a = axq[(tn+i)*101 + k];
                acc[i][0] = fmaf(a, w0, acc[i][0]);
                acc[i][1] = fmaf(a, w1, acc[i][1]);
                acc[i][2] = fmaf(a, w2, acc[i][2]);
            }
        }
        #pragma unroll
        for (int j = 0; j < 3; ++j) {
            const int col = tc + j, hh = col / HD, d = col - hh*HD;
            #pragma unroll
            for (int i = 0; i < 4; ++i) {
                const int n = n0 + tn + i;
                u16 hi, lo;
                split1(acc[i][j] * QSCALE, hi, lo);
                const size_t dst = ((size_t)(b*NH + hh)*Nn + n)*32 + d;
                qhp[dst] = hi; qlp[dst] = lo;
            }
        }
    }

    // ---- phase B: k halves ----
    __syncthreads();
    for (int e = tid; e < 96*96; e += 256) lw[(e/96)*97 + (e%96)] = w_kv[(e/96)*192 + (e%96)];
    __syncthreads();
    {
        float a1c[4][3] = {}, a2c[4][3] = {};
        for (int k = 0; k < 96; ++k) {
            const float w0 = lw[k*97 + tc + 0];
            const float w1 = lw[k*97 + tc + 1];
            const float w2 = lw[k*97 + tc + 2];
            #pragma unroll
            for (int i = 0; i < 4; ++i) {
                const float a1 = amx[(tn+i)*101 + k];
                const float a2 = aav[(tn+i)*101 + k];
                a1c[i][0] = fmaf(a1, w0, a1c[i][0]);
                a1c[i][1] = fmaf(a1, w1, a1c[i][1]);
                a1c[i][2] = fmaf(a1, w2, a1c[i][2]);
                a2c[i][0] = fmaf(a2, w0, a2c[i][0]);
                a2c[i][1] = fmaf(a2, w1, a2c[i][1]);
                a2c[i][2] = fmaf(a2, w2, a2c[i][2]);
            }
        }
        #pragma unroll
        for (int j = 0; j < 3; ++j) {
            const int col = tc + j, hh = col / HD, d = col - hh*HD;
            #pragma unroll
            for (int i = 0; i < 4; ++i) {
                const int n = n0 + tn + i;
                const int rho = (n & ~31) | ((n & 4) << 2) | ((n & 24) >> 1) | (n & 3);
                const size_t dst = ((size_t)(b*NH + hh)*Nn + rho)*32 + d;
                u16 hi, lo;
                split1(a1c[i][j], hi, lo); k1h[dst] = hi; k1l[dst] = lo;
                split1(a2c[i][j], hi, lo); k2h[dst] = hi; k2l[dst] = lo;
            }
        }
    }

    // ---- phase C: v halves (transposed store) ----
    __syncthreads();
    for (int e = tid; e < 96*96; e += 256) lw[(e/96)*97 + (e%96)] = w_kv[(e/96)*192 + 96 + (e%96)];
    __syncthreads();
    {
        float a1c[4][3] = {}, a2c[4][3] = {};
        for (int k = 0; k < 96; ++k) {
            const float w0 = lw[k*97 + tc + 0];
            const float w1 = lw[k*97 + tc + 1];
            const float w2 = lw[k*97 + tc + 2];
            #pragma unroll
            for (int i = 0; i < 4; ++i) {
                const float a1 = amx[(tn+i)*101 + k];
                const float a2 = aav[(tn+i)*101 + k];
                a1c[i][0] = fmaf(a1, w0, a1c[i][0]);
                a1c[i][1] = fmaf(a1, w1, a1c[i][1]);
                a1c[i][2] = fmaf(a1, w2, a1c[i][2]);
                a2c[i][0] = fmaf(a2, w0, a2c[i][0]);
                a2c[i][1] = fmaf(a2, w1, a2c[i][1]);
                a2c[i][2] = fmaf(a2, w2, a2c[i][2]);
            }
        }
        #pragma unroll
        for (int j = 0; j < 3; ++j) {
            const int col = tc + j, hh = col / HD, d = col - hh*HD;
            #pragma unroll
            for (int i = 0; i < 4; ++i) {
                const int n = n0 + tn + i;
                const size_t dst = ((size_t)(b*NH + hh)*32 + d)*Nn + n;
                u16 hi, lo;
                split1(a1c[i][j], hi, lo); v1h[dst] = hi; v1l[dst] = lo;
                split1(a2c[i][j], hi, lo); v2h[dst] = hi; v2l[dst] = lo;
            }
        }
    }

    // ---- pad zeroing: q/k d=24..31 (must be finite-zero: 0*NaN hazard), v rows 24..31
    for (int e = tid; e < 1024; e += 256) {
        const int hh = e >> 8;
        const int nn = (e >> 3) & 31;
        const int d  = 24 + (e & 7);
        const int n  = n0 + nn;
        const size_t kd = ((size_t)(b*NH + hh)*Nn + n)*32 + d;
        qhp[kd] = 0; qlp[kd] = 0;
        k1h[kd] = 0; k1l[kd] = 0; k2h[kd] = 0; k2l[kd] = 0;
        const size_t vd = ((size_t)(b*NH + hh)*32 + d)*Nn + n;
        v1h[vd] = 0; v1l[vd] = 0; v2h[vd] = 0; v2l[vd] = 0;
    }
}

// ---------------------------------------------------------------------------
// MFMA flash attention, both branches. Block = 32 queries; 4 waves =
// 2 q-groups x 2 key-halves (512 keys each, 8 tiles of 64). Branches are
// processed SEQUENTIALLY (register diet -> 4 waves/SIMD with
// __launch_bounds__(256,4)); exp->pack->PV streamed per 32-key chunk.
// Wave pairs merge online-softmax state via LDS (stride-21 pad).
// ---------------------------------------------------------------------------
__global__ __launch_bounds__(256, 4) void attn_kernel(
    const u16* __restrict__ qhp, const u16* __restrict__ qlp,
    const u16* __restrict__ k1h, const u16* __restrict__ k1l,
    const u16* __restrict__ k2h, const u16* __restrict__ k2l,
    const u16* __restrict__ v1h, const u16* __restrict__ v1l,
    const u16* __restrict__ v2h, const u16* __restrict__ v2l,
    const float* __restrict__ bias_table, float* __restrict__ osum)
{
    const int tid = threadIdx.x;
    const int h = blockIdx.y, b = blockIdx.z;
    const int bh = b*NH + h;

    __shared__ float biasl[3969];
    __shared__ float mrg[2][64][21];   // [qg][lane][2 branches x (m,l,o[8]) = 20, pad 21]

    for (int e = tid; e < 3969; e += 256) biasl[e] = bias_table[e*NH + h];
    __syncthreads();

    const int lane = tid & 63;
    const int wave = tid >> 6;
    const int qg = wave & 1;      // query group within block
    const int ks = wave >> 1;     // key half
    const int lg = lane >> 4;     // lane group 0..3
    const int lr = lane & 15;
    const int q  = blockIdx.x*32 + qg*16 + lr;
    const int yn = q >> 5, xn = q & 31;

    const size_t qoff = ((size_t)bh*Nn + q)*32 + lg*8;
    const bh8 qfh = *(const bh8*)(qhp + qoff);
    const bh8 qfl = *(const bh8*)(qlp + qoff);

    const size_t kbase = ((size_t)bh*Nn + lr)*32 + lg*8;
    const size_t vbase = ((size_t)bh*32 + lr)*Nn + lg*8;
    const u16* kph[2] = { k1h + kbase, k2h + kbase };
    const u16* kpl[2] = { k1l + kbase, k2l + kbase };
    const u16* vph[2] = { v1h + vbase, v2h + vbase };
    const u16* vpl[2] = { v1l + vbase, v2l + vbase };

    const fx4 zero = {0.0f, 0.0f, 0.0f, 0.0f};
    fx4 oo[2][2];
    float mm[2], ll[2];

    #pragma unroll
    for (int br = 0; br < 2; ++br) {
        oo[br][0] = zero; oo[br][1] = zero;
        float m = -3.0e38f, l = 0.0f;
        const u16* kh = kph[br]; const u16* kl = kpl[br];
        const u16* vh = vph[br]; const u16* vl = vpl[br];

        for (int it = ks*8; it < ks*8 + 8; ++it) {
            const int kb = it*64;
            fx4 s[4];
            #pragma unroll
            for (int t = 0; t < 4; ++t) {
                const int ro = (kb + t*16)*32;
                const bh8 ah = *(const bh8*)(kh + ro);
                const bh8 al = *(const bh8*)(kl + ro);
                // actual key of C elem (t, lg, j): kb + 32*(t>>1) + 4*(t&1) + 8*lg + j
                const int ym   = (kb >> 5) + (t >> 1);
                const int xmb  = (t & 1)*4 + lg*8;
                const int rowb = (yn - ym + 31)*63 + (xn + 31) - xmb;
                fx4 u;
                #pragma unroll
                for (int j = 0; j < 4; ++j) u[j] = biasl[rowb - j];
                u = MFMA16(ah, qfh, u);
                u = MFMA16(ah, qfl, u);
                u = MFMA16(al, qfh, u);
                s[t] = u;
            }

            // tile max over this lane's 16 keys, then across the 4 lane-groups
            float tmax = s[0][0];
            #pragma unroll
            for (int t = 0; t < 4; ++t)
                #pragma unroll
                for (int j = 0; j < 4; ++j)
                    if (t | j) tmax = fmaxf(tmax, s[t][j]);
            tmax = fmaxf(tmax, __shfl_xor(tmax, 16));
            tmax = fmaxf(tmax, __shfl_xor(tmax, 32));
            const float M = fmaxf(m, tmax);
            if (!__all(tmax <= m)) {     // skip is bit-exact (c would be 1.0)
                const float c = __expf(m - M);
                l *= c;
                oo[br][0] *= c; oo[br][1] *= c;
            }
            m = M;

            #pragma unroll
            for (int ch = 0; ch < 2; ++ch) {
                const float e0 = __expf(s[2*ch  ][0] - M);
                const float e1 = __expf(s[2*ch  ][1] - M);
                const float e2 = __expf(s[2*ch  ][2] - M);
                const float e3 = __expf(s[2*ch  ][3] - M);
                const float e4 = __expf(s[2*ch+1][0] - M);
                const float e5 = __expf(s[2*ch+1][1] - M);
                const float e6 = __expf(s[2*ch+1][2] - M);
                const float e7 = __expf(s[2*ch+1][3] - M);
                l += ((e0 + e1) + (e2 + e3)) + ((e4 + e5) + (e6 + e7));
                PackU ph_, pl_;
                split2(e0, e1, ph_.u[0], pl_.u[0]);
                split2(e2, e3, ph_.u[1], pl_.u[1]);
                split2(e4, e5, ph_.u[2], pl_.u[2]);
                split2(e6, e7, ph_.u[3], pl_.u[3]);
                const int vo0 = kb + ch*32;
                #pragma unroll
                for (int dt = 0; dt < 2; ++dt) {
                    const size_t vo = (size_t)(dt*16)*Nn + vo0;
                    const bh8 wh = *(const bh8*)(vh + vo);
                    const bh8 wl = *(const bh8*)(vl + vo);
                    oo[br][dt] = MFMA16(wh, ph_.s, oo[br][dt]);
                    oo[br][dt] = MFMA16(wh, pl_.s, oo[br][dt]);
                    oo[br][dt] = MFMA16(wl, ph_.s, oo[br][dt]);
                }
            }
        }
        mm[br] = m; ll[br] = l;
    }

    // ---- merge the two key-halves (flash merge), then output ----
    if (ks == 1) {
        float* mb = &mrg[qg][lane][0];
        #pragma unroll
        for (int br = 0; br < 2; ++br) {
            mb[br*10 + 0] = mm[br];
            mb[br*10 + 1] = ll[br];
            #pragma unroll
            for (int j = 0; j < 4; ++j) {
                mb[br*10 + 2 + j] = oo[br][0][j];
                mb[br*10 + 6 + j] = oo[br][1][j];
            }
        }
    }
    __syncthreads();
    if (ks == 0) {
        const float* mb = &mrg[qg][lane][0];
        float li[2]; fx4 om[2][2];
        #pragma unroll
        for (int br = 0; br < 2; ++br) {
            const float mo  = mb[br*10 + 0];
            const float lo2 = mb[br*10 + 1];
            const float M  = fmaxf(mm[br], mo);
            const float ca = __expf(mm[br] - M);
            const float cb = __expf(mo - M);
            float lm = ll[br]*ca + lo2*cb;
            #pragma unroll
            for (int dt = 0; dt < 2; ++dt)
                #pragma unroll
                for (int j = 0; j < 4; ++j)
                    om[br][dt][j] = oo[br][dt][j]*ca + mb[br*10 + 2 + dt*4 + j]*cb;
            lm += __shfl_xor(lm, 16);
            lm += __shfl_xor(lm, 32);
            li[br] = 1.0f / lm;
        }
        float* orow = osum + ((size_t)b*Nn + q)*Cc + h*HD;
        #pragma unroll
        for (int dt = 0; dt < 2; ++dt)
            #pragma unroll
            for (int j = 0; j < 4; ++j) {
                const int d = dt*16 + lg*4 + j;
                if (d < HD) orow[d] = om[0][dt][j]*li[0] + om[1][dt][j]*li[1];
            }
    }
}

// ---------------------------------------------------------------------------
__global__ __launch_bounds__(256) void fusew_kernel(
    const float* __restrict__ w_proj, const float* __restrict__ b_proj,
    const float* __restrict__ w_out, const float* __restrict__ b_out,
    float* __restrict__ wf, float* __restrict__ bf)
{
    const int e = blockIdx.x * 256 + threadIdx.x;
    if (e < Cc * Dd) {
        const int c = e / Dd, o = e - c*Dd;
        const float* wp = w_proj + c*Cc;
        const float* wo = w_out + (size_t)o*Cc;
        float acc = 0.0f;
        for (int c2 = 0; c2 < Cc; ++c2) acc = fmaf(wp[c2], wo[c2], acc);
        wf[e] = acc;
    }
    if (e < Dd) {
        const float* wo = w_out + (size_t)e*Cc;
        float acc = 0.0f;
        for (int c = 0; c < Cc; ++c) acc = fmaf(b_proj[c], wo[c], acc);
        bf[e] = b_out[e] + 2.0f * acc;
    }
}

// ---------------------------------------------------------------------------
__global__ __launch_bounds__(256) void outgemm_kernel(
    const float* __restrict__ osum, const float* __restrict__ wf, const float* __restrict__ bf,
    float* __restrict__ outs)
{
    const int tid = threadIdx.x;
    const int n0 = blockIdx.x * 32;
    const int b  = blockIdx.y;
    __shared__ float ax[32*101];
    __shared__ float lw[96*132];
    for (int e = tid; e < 32*96; e += 256) {
        const int n = e / 96, c = e - n*96;
        ax[n*101 + c] = osum[((size_t)b*Nn + n0 + n)*Cc + c];
    }
    const int tn = (tid & 7) * 4;
    const int tj = (tid >> 3) * 4;
    for (int o0 = 0; o0 < Dd; o0 += 128) {
        __syncthreads();
        for (int e = tid; e < 96*128; e += 256) {
            const int c = e >> 7, j = e & 127;
            lw[c*132 + j] = wf[(size_t)c*Dd + o0 + j];
        }
        __syncthreads();
        float acc[4][4] = {};
        for (int c = 0; c < 96; ++c) {
            const float4 wv = *(const float4*)&lw[c*132 + tj];
            #pragma unroll
            for (int i = 0; i < 4; ++i) {
                const float a = ax[(tn+i)*101 + c];
                acc[i][0] = fmaf(a, wv.x, acc[i][0]);
                acc[i][1] = fmaf(a, wv.y, acc[i][1]);
                acc[i][2] = fmaf(a, wv.z, acc[i][2]);
                acc[i][3] = fmaf(a, wv.w, acc[i][3]);
            }
        }
        #pragma unroll
        for (int j = 0; j < 4; ++j) {
            const int o = o0 + tj + j;
            const float bb = bf[o];
            #pragma unroll
            for (int i = 0; i < 4; ++i)
                outs[((size_t)b*Dd + o)*Nn + n0 + tn + i] = acc[i][j] + bb;
        }
    }
}

// ---------------------------------------------------------------------------
__global__ __launch_bounds__(256) void upsample_kernel(
    const float* __restrict__ src, float* __restrict__ dst)
{
    const int gid = blockIdx.x * 256 + threadIdx.x;
    const int ox4 = gid & 31;
    const int oy  = (gid >> 5) & 127;
    const int bc  = gid >> 12;
    const float* s = src + (size_t)bc * 1024;
    const float sy = oy * (31.0f / 127.0f);
    const int y0 = (int)sy;
    const int y1 = min(y0 + 1, 31);
    const float wy = sy - (float)y0;
    const float* r0 = s + y0 * 32;
    const float* r1 = s + y1 * 32;
    float res[4];
    #pragma unroll
    for (int j = 0; j < 4; ++j) {
        const int ox = ox4 * 4 + j;
        const float sx = ox * (31.0f / 127.0f);
        const int x0 = (int)sx;
        const int x1 = min(x0 + 1, 31);
        const float wx = sx - (float)x0;
        const float t0 = r0[x0] * (1.0f - wx) + r0[x1] * wx;
        const float t1 = r1[x0] * (1.0f - wx) + r1[x1] * wx;
        res[j] = t0 * (1.0f - wy) + t1 * wy;
    }
    *(float4*)(dst + (size_t)gid * 4) = make_float4(res[0], res[1], res[2], res[3]);
}

// ---------------------------------------------------------------------------
extern "C" void kernel_launch(void* const* d_in, const int* in_sizes, int n_in,
                              void* d_out, int out_size, void* d_ws, size_t ws_size,
                              hipStream_t stream)
{
    const float* x      = (const float*)d_in[0];
    const float* w_le   = (const float*)d_in[1];
    const float* b_le   = (const float*)d_in[2];
    const float* bn_le  = (const float*)d_in[3];
    const float* w_max  = (const float*)d_in[4];
    const float* b_max  = (const float*)d_in[5];
    const float* bn_max = (const float*)d_in[6];
    const float* w_avg  = (const float*)d_in[7];
    const float* b_avg  = (const float*)d_in[8];
    const float* bn_avg = (const float*)d_in[9];
    const float* btab   = (const float*)d_in[10];
    const float* w_q    = (const float*)d_in[11];
    const float* w_kv   = (const float*)d_in[12];
    const float* w_proj = (const float*)d_in[13];
    const float* b_proj = (const float*)d_in[14];
    const float* w_out  = (const float*)d_in[15];
    const float* b_out  = (const float*)d_in[16];
    (void)in_sizes; (void)n_in; (void)out_size; (void)ws_size;

    float* ws = (float*)d_ws;
    const size_t T  = (size_t)Bb * Cc * Nn;          // 786432 floats
    const size_t AS = (size_t)Bb * NH * Nn * 32;     // 1048576 u16 per bf16 array

    float* xq   = ws + 0*T;
    float* tmx  = ws + 1*T;
    float* tav  = ws + 2*T;
    u16*  bb16  = (u16*)(ws + 3*T);                  // 10 bf16 arrays, 20 MB
    u16* qh  = bb16 + 0*AS;  u16* ql  = bb16 + 1*AS;
    u16* k1h = bb16 + 2*AS;  u16* k1l = bb16 + 3*AS;
    u16* k2h = bb16 + 4*AS;  u16* k2l = bb16 + 5*AS;
    u16* v1h = bb16 + 6*AS;  u16* v1l = bb16 + 7*AS;
    u16* v2h = bb16 + 8*AS;  u16* v2l = bb16 + 9*AS;
    float* osum = (float*)(bb16 + 10*AS);
    float* wf   = osum + T;
    float* bf   = wf + (size_t)Cc*Dd;
    float* outs = ws;   // aliases [ws, ws+4T): stem bufs + head of bf16 region,
                        // all dead once outgemm runs (stream-serial)

    stem_kernel<<<dim3(4, 96, 8), 256, 0, stream>>>(
        x, w_le, b_le, bn_le, w_max, b_max, bn_max, w_avg, b_avg, bn_avg, xq, tmx, tav);
    proj_kernel<<<dim3(32, 8), 256, 0, stream>>>(
        xq, tmx, tav, w_q, w_kv, qh, ql, k1h, k1l, k2h, k2l, v1h, v1l, v2h, v2l);
    fusew_kernel<<<dim3(144), 256, 0, stream>>>(w_proj, b_proj, w_out, b_out, wf, bf);
    attn_kernel<<<dim3(32, 4, 8), 256, 0, stream>>>(
        qh, ql, k1h, k1l, k2h, k2l, v1h, v1l, v2h, v2l, btab, osum);
    outgemm_kernel<<<dim3(32, 8), 256, 0, stream>>>(osum, wf, bf, outs);
    upsample_kernel<<<dim3(49152), 256, 0, stream>>>(outs, (float*)d_out);
}

// Round 3
// 539.070 us; speedup vs baseline: 1.0128x; 1.0128x over previous
//
#include <hip/hip_runtime.h>
#include <math.h>

namespace {
constexpr int Bb  = 8;
constexpr int Dd  = 384;
constexpr int HIN = 128;
constexpr int Cc  = 96;
constexpr int Nn  = 1024;
constexpr int NH  = 4;
constexpr int HD  = 24;
}
#define BN_EPS 1e-5f
#define QSCALE 0.20412414523193154f  /* 24^-0.5 */

typedef unsigned short u16;
typedef unsigned int   u32;
typedef __attribute__((ext_vector_type(8))) short bh8;   // 8 bf16 = 4 VGPR (MFMA A/B frag)
typedef __attribute__((ext_vector_type(4))) float fx4;   // MFMA C/D frag

#define MFMA16(a,b,c) __builtin_amdgcn_mfma_f32_16x16x32_bf16((a),(b),(c),0,0,0)

union PackU { u32 u[4]; bh8 s; };

// truncated hi/lo bf16 split: v == hi + lo to ~2^-16 relative
__device__ __forceinline__ void split1(float v, u16& hi, u16& lo) {
    const u32 bv = __float_as_uint(v);
    const u32 hb = bv & 0xffff0000u;
    hi = (u16)(bv >> 16);
    const float r = v - __uint_as_float(hb);   // exact (same exponent)
    lo = (u16)(__float_as_uint(r) >> 16);
}
// pack two floats into one dword of 2 bf16 (x->lo half, y->hi half) + residual pack
__device__ __forceinline__ void split2(float x, float y, u32& hi, u32& lo) {
    const u32 bx = __float_as_uint(x), by = __float_as_uint(y);
    const u32 hx = bx & 0xffff0000u, hy = by & 0xffff0000u;
    hi = (hx >> 16) | hy;
    const float rx = x - __uint_as_float(hx);
    const float ry = y - __uint_as_float(hy);
    lo = (__float_as_uint(rx) >> 16) | (__float_as_uint(ry) & 0xffff0000u);
}

__device__ __forceinline__ float bn_relu6(float y, const float* __restrict__ bn, int c) {
    float gam = bn[c], bet = bn[Cc + c], mu = bn[2*Cc + c], var = bn[3*Cc + c];
    float s = gam / sqrtf(var + BN_EPS);
    float r = (y - mu) * s + bet;
    return fminf(fmaxf(r, 0.0f), 6.0f);
}

// ---------------------------------------------------------------------------
// Stem: fused (grouped 4x4/s4 conv | 4x4 maxpool+grouped1x1 | 4x4 avgpool+grouped1x1)
// Extra blocks (blockIdx.y == 96, 32 blocks): fusew (w_proj x w_out) + bias
// table transpose btr[h][3969] (so attn's LDS fill is coalesced).
// ---------------------------------------------------------------------------
__global__ __launch_bounds__(256) void stem_kernel(
    const float* __restrict__ x, const float* __restrict__ w_le,
    const float* __restrict__ b_le, const float* __restrict__ bn_le,
    const float* __restrict__ w_max, const float* __restrict__ b_max, const float* __restrict__ bn_max,
    const float* __restrict__ w_avg, const float* __restrict__ b_avg, const float* __restrict__ bn_avg,
    const float* __restrict__ w_proj, const float* __restrict__ b_proj,
    const float* __restrict__ w_out, const float* __restrict__ b_out,
    const float* __restrict__ btab,
    float* __restrict__ xq, float* __restrict__ tmx, float* __restrict__ tav,
    float* __restrict__ wf, float* __restrict__ bf, float* __restrict__ btr)
{
    const int tid = threadIdx.x;
    if (blockIdx.y == 96) {
        // ---- fused-weight + bias-transpose side work ----
        const int tg = (blockIdx.z*4 + blockIdx.x)*256 + tid;   // 0..8191
        for (int e = tg; e < Cc*Dd; e += 8192) {
            const int c = e / Dd, o = e - c*Dd;
            const float* wp = w_proj + c*Cc;
            const float* wo = w_out + (size_t)o*Cc;
            float acc = 0.0f;
            for (int c2 = 0; c2 < Cc; ++c2) acc = fmaf(wp[c2], wo[c2], acc);
            wf[e] = acc;
        }
        if (tg < Dd) {
            const float* wo = w_out + (size_t)tg*Cc;
            float acc = 0.0f;
            for (int c = 0; c < Cc; ++c) acc = fmaf(b_proj[c], wo[c], acc);
            bf[tg] = b_out[tg] + 2.0f * acc;
        }
        for (int e = tg; e < 3969*NH; e += 8192) {
            const int hh = e / 3969, i = e - hh*3969;
            btr[e] = btab[i*NH + hh];
        }
        return;
    }
    const int n = blockIdx.x * 256 + tid;
    const int g = blockIdx.y;
    const int b = blockIdx.z;
    const int oh = n >> 5, ow = n & 31;

    const float* xb = x + (((size_t)b * Dd + 4*g) * HIN + 4*oh) * HIN + 4*ow;
    float conv = 0.0f, mxv = 0.0f, avv = 0.0f;
    #pragma unroll
    for (int i = 0; i < 4; ++i) {
        float cmax = -3.0e38f, csum = 0.0f;
        #pragma unroll
        for (int kh = 0; kh < 4; ++kh) {
            const float4 v = *(const float4*)(xb + ((size_t)i * HIN + kh) * HIN);
            const float* wl = w_le + (((g*4 + i)*4 + kh) * 4);
            conv = fmaf(v.x, wl[0], conv);
            conv = fmaf(v.y, wl[1], conv);
            conv = fmaf(v.z, wl[2], conv);
            conv = fmaf(v.w, wl[3], conv);
            cmax = fmaxf(cmax, fmaxf(fmaxf(v.x, v.y), fmaxf(v.z, v.w)));
            csum += (v.x + v.y) + (v.z + v.w);
        }
        mxv = fmaf(cmax, w_max[g*4 + i], mxv);
        avv = fmaf(csum * (1.0f/16.0f), w_avg[g*4 + i], avv);
    }
    const float xqv = bn_relu6(conv + b_le[g], bn_le, g);
    const float tm  = bn_relu6(mxv  + b_max[g], bn_max, g);
    const float ta  = bn_relu6(avv  + b_avg[g], bn_avg, g);
    const size_t o = ((size_t)b * Cc + g) * Nn + n;
    xq[o] = xqv; tmx[o] = tm; tav[o] = ta;
}

// ---------------------------------------------------------------------------
// Projections -> bf16 hi/lo MFMA operand layouts. 5-way phase split
// (z = {q, k1, k2, v1, v2}) so each block stages ONE activation tile + ONE
// 96x96 weight: LDS 49 KB -> 3 blocks/CU (was 1), per-block work / 5.
//   Q:  [bh][n][32]  (d pad 24..31 = 0; QSCALE pre-applied)
//   K:  [bh][rho(n)][32]  rows permuted within each 32-chunk (PV slot match)
//   V^T:[bh][32][n]  (d rows 24..31 = 0)
// ---------------------------------------------------------------------------
__global__ __launch_bounds__(256, 3) void proj_kernel(
    const float* __restrict__ xq, const float* __restrict__ tmx, const float* __restrict__ tav,
    const float* __restrict__ w_q, const float* __restrict__ w_kv,
    u16* __restrict__ qhp, u16* __restrict__ qlp,
    u16* __restrict__ k1h, u16* __restrict__ k1l, u16* __restrict__ k2h, u16* __restrict__ k2l,
    u16* __restrict__ v1h, u16* __restrict__ v1l, u16* __restrict__ v2h, u16* __restrict__ v2l)
{
    const int tid   = threadIdx.x;
    const int n0    = blockIdx.x * 32;
    const int b     = blockIdx.y;
    const int phase = blockIdx.z;          // 0=q 1=k1 2=k2 3=v1 4=v2
    __shared__ float A[32*97];
    __shared__ float lw[96*96];

    const float* asrc = (phase == 0) ? xq : ((phase == 1 || phase == 3) ? tmx : tav);
    for (int e = tid; e < 96*32; e += 256) {
        const int c = e >> 5, j = e & 31;
        A[j*97 + c] = asrc[((size_t)b * Cc + c) * Nn + n0 + j];
    }
    const float* wsrc = (phase == 0) ? w_q : w_kv;
    const int RS = (phase == 0) ? 96 : 192;
    const int WO = (phase <= 2) ? 0 : 96;
    for (int e = tid; e < 96*96; e += 256)
        lw[e] = wsrc[(e/96)*RS + WO + (e%96)];
    __syncthreads();

    const int tn = (tid & 7) * 4;   // 4 rows (n)
    const int tc = (tid >> 3) * 3;  // 3 cols

    float acc[4][3] = {};
    for (int k = 0; k < 96; ++k) {
        const float w0 = lw[k*96 + tc + 0];
        const float w1 = lw[k*96 + tc + 1];
        const float w2 = lw[k*96 + tc + 2];
        #pragma unroll
        for (int i = 0; i < 4; ++i) {
            const float a = A[(tn+i)*97 + k];
            acc[i][0] = fmaf(a, w0, acc[i][0]);
            acc[i][1] = fmaf(a, w1, acc[i][1]);
            acc[i][2] = fmaf(a, w2, acc[i][2]);
        }
    }

    u16* dh; u16* dl;
    if      (phase == 0) { dh = qhp; dl = qlp; }
    else if (phase == 1) { dh = k1h; dl = k1l; }
    else if (phase == 2) { dh = k2h; dl = k2l; }
    else if (phase == 3) { dh = v1h; dl = v1l; }
    else                 { dh = v2h; dl = v2l; }

    #pragma unroll
    for (int j = 0; j < 3; ++j) {
        const int col = tc + j, hh = col / HD, d = col - hh*HD;
        #pragma unroll
        for (int i = 0; i < 4; ++i) {
            const int n = n0 + tn + i;
            float v = acc[i][j];
            size_t dst;
            if (phase == 0) {
                v *= QSCALE;
                dst = ((size_t)(b*NH + hh)*Nn + n)*32 + d;
            } else if (phase <= 2) {
                const int rho = (n & ~31) | ((n & 4) << 2) | ((n & 24) >> 1) | (n & 3);
                dst = ((size_t)(b*NH + hh)*Nn + rho)*32 + d;
            } else {
                dst = ((size_t)(b*NH + hh)*32 + d)*Nn + n;
            }
            u16 hi, lo;
            split1(v, hi, lo);
            dh[dst] = hi; dl[dst] = lo;
        }
    }

    // pad zeroing (d = 24..31 must be finite-zero: 0*NaN hazard)
    for (int e = tid; e < 1024; e += 256) {
        const int hh = e >> 8;
        const int nn = (e >> 3) & 31;
        const int d  = 24 + (e & 7);
        const int n  = n0 + nn;
        const size_t dst = (phase <= 2)
            ? ((size_t)(b*NH + hh)*Nn + n)*32 + d
            : ((size_t)(b*NH + hh)*32 + d)*Nn + n;
        dh[dst] = 0; dl[dst] = 0;
    }
}

// ---------------------------------------------------------------------------
// MFMA flash attention. Block = 32 queries; 4 waves = 2 q-groups x 2
// key-halves. Branches sequential (register-lean). T13 defer-max (THR=8):
// common path has NO cross-lane reduce / NO O-rescale -- lane-local max +
// wave-uniform __all check only; p <= e^8 is exact under the f32 accum and
// scale-invariant for the hi/lo bf16 packing. Key-halves merge via LDS.
// ---------------------------------------------------------------------------
__global__ __launch_bounds__(256, 4) void attn_kernel(
    const u16* __restrict__ qhp, const u16* __restrict__ qlp,
    const u16* __restrict__ k1h, const u16* __restrict__ k1l,
    const u16* __restrict__ k2h, const u16* __restrict__ k2l,
    const u16* __restrict__ v1h, const u16* __restrict__ v1l,
    const u16* __restrict__ v2h, const u16* __restrict__ v2l,
    const float* __restrict__ btr, float* __restrict__ osum)
{
    const int tid = threadIdx.x;
    const int h = blockIdx.y, b = blockIdx.z;
    const int bh = b*NH + h;

    __shared__ float biasl[3969];
    __shared__ float mrg[2][64][21];   // [qg][lane][2 branches x (m,l,o[8]) = 20, pad 21]

    for (int e = tid; e < 3969; e += 256) biasl[e] = btr[h*3969 + e];
    __syncthreads();

    const int lane = tid & 63;
    const int wave = tid >> 6;
    const int qg = wave & 1;      // query group within block
    const int ks = wave >> 1;     // key half
    const int lg = lane >> 4;     // lane group 0..3
    const int lr = lane & 15;
    const int q  = blockIdx.x*32 + qg*16 + lr;
    const int yn = q >> 5, xn = q & 31;

    const size_t qoff = ((size_t)bh*Nn + q)*32 + lg*8;
    const bh8 qfh = *(const bh8*)(qhp + qoff);
    const bh8 qfl = *(const bh8*)(qlp + qoff);

    const size_t kbase = ((size_t)bh*Nn + lr)*32 + lg*8;
    const size_t vbase = ((size_t)bh*32 + lr)*Nn + lg*8;
    const u16* kph[2] = { k1h + kbase, k2h + kbase };
    const u16* kpl[2] = { k1l + kbase, k2l + kbase };
    const u16* vph[2] = { v1h + vbase, v2h + vbase };
    const u16* vpl[2] = { v1l + vbase, v2l + vbase };

    const fx4 zero = {0.0f, 0.0f, 0.0f, 0.0f};
    fx4 oo[2][2];
    float mm[2], ll[2];

    #pragma unroll
    for (int br = 0; br < 2; ++br) {
        oo[br][0] = zero; oo[br][1] = zero;
        float m = -3.0e38f, l = 0.0f;
        const u16* kh = kph[br]; const u16* kl = kpl[br];
        const u16* vh = vph[br]; const u16* vl = vpl[br];

        for (int it = ks*8; it < ks*8 + 8; ++it) {
            const int kb = it*64;
            fx4 s[4];
            #pragma unroll
            for (int t = 0; t < 4; ++t) {
                const int ro = (kb + t*16)*32;
                const bh8 ah = *(const bh8*)(kh + ro);
                const bh8 al = *(const bh8*)(kl + ro);
                // actual key of C elem (t, lg, j): kb + 32*(t>>1) + 4*(t&1) + 8*lg + j
                const int ym   = (kb >> 5) + (t >> 1);
                const int xmb  = (t & 1)*4 + lg*8;
                const int rowb = (yn - ym + 31)*63 + (xn + 31) - xmb;
                fx4 u;
                #pragma unroll
                for (int j = 0; j < 4; ++j) u[j] = biasl[rowb - j];
                u = MFMA16(ah, qfh, u);
                u = MFMA16(ah, qfl, u);
                u = MFMA16(al, qfh, u);
                s[t] = u;
            }

            // lane-local max over this lane's 16 keys
            float lmax = fmaxf(fmaxf(s[0][0], s[0][1]), fmaxf(s[0][2], s[0][3]));
            #pragma unroll
            for (int t = 1; t < 4; ++t)
                lmax = fmaxf(lmax, fmaxf(fmaxf(s[t][0], s[t][1]), fmaxf(s[t][2], s[t][3])));

            // T13 defer-max: only rescale when some lane grows past m + 8
            if (!__all(lmax <= m + 8.0f)) {
                float tmax = lmax;
                tmax = fmaxf(tmax, __shfl_xor(tmax, 16));
                tmax = fmaxf(tmax, __shfl_xor(tmax, 32));
                const float M = fmaxf(m, tmax);
                const float c = __expf(m - M);
                l *= c;
                oo[br][0] *= c; oo[br][1] *= c;
                m = M;
            }

            #pragma unroll
            for (int ch = 0; ch < 2; ++ch) {
                const float e0 = __expf(s[2*ch  ][0] - m);
                const float e1 = __expf(s[2*ch  ][1] - m);
                const float e2 = __expf(s[2*ch  ][2] - m);
                const float e3 = __expf(s[2*ch  ][3] - m);
                const float e4 = __expf(s[2*ch+1][0] - m);
                const float e5 = __expf(s[2*ch+1][1] - m);
                const float e6 = __expf(s[2*ch+1][2] - m);
                const float e7 = __expf(s[2*ch+1][3] - m);
                l += ((e0 + e1) + (e2 + e3)) + ((e4 + e5) + (e6 + e7));
                PackU ph_, pl_;
                split2(e0, e1, ph_.u[0], pl_.u[0]);
                split2(e2, e3, ph_.u[1], pl_.u[1]);
                split2(e4, e5, ph_.u[2], pl_.u[2]);
                split2(e6, e7, ph_.u[3], pl_.u[3]);
                const int vo0 = kb + ch*32;
                #pragma unroll
                for (int dt = 0; dt < 2; ++dt) {
                    const size_t vo = (size_t)(dt*16)*Nn + vo0;
                    const bh8 wh = *(const bh8*)(vh + vo);
                    const bh8 wl = *(const bh8*)(vl + vo);
                    oo[br][dt] = MFMA16(wh, ph_.s, oo[br][dt]);
                    oo[br][dt] = MFMA16(wh, pl_.s, oo[br][dt]);
                    oo[br][dt] = MFMA16(wl, ph_.s, oo[br][dt]);
                }
            }
        }
        mm[br] = m; ll[br] = l;
    }

    // ---- merge the two key-halves (flash merge), then output ----
    if (ks == 1) {
        float* mb = &mrg[qg][lane][0];
        #pragma unroll
        for (int br = 0; br < 2; ++br) {
            mb[br*10 + 0] = mm[br];
            mb[br*10 + 1] = ll[br];
            #pragma unroll
            for (int j = 0; j < 4; ++j) {
                mb[br*10 + 2 + j] = oo[br][0][j];
                mb[br*10 + 6 + j] = oo[br][1][j];
            }
        }
    }
    __syncthreads();
    if (ks == 0) {
        const float* mb = &mrg[qg][lane][0];
        float li[2]; fx4 om[2][2];
        #pragma unroll
        for (int br = 0; br < 2; ++br) {
            const float mo  = mb[br*10 + 0];
            const float lo2 = mb[br*10 + 1];
            const float M  = fmaxf(mm[br], mo);
            const float ca = __expf(mm[br] - M);
            const float cb = __expf(mo - M);
            float lm = ll[br]*ca + lo2*cb;
            #pragma unroll
            for (int dt = 0; dt < 2; ++dt)
                #pragma unroll
                for (int j = 0; j < 4; ++j)
                    om[br][dt][j] = oo[br][dt][j]*ca + mb[br*10 + 2 + dt*4 + j]*cb;
            lm += __shfl_xor(lm, 16);
            lm += __shfl_xor(lm, 32);
            li[br] = 1.0f / lm;
        }
        float* orow = osum + ((size_t)b*Nn + q)*Cc + h*HD;
        #pragma unroll
        for (int dt = 0; dt < 2; ++dt)
            #pragma unroll
            for (int j = 0; j < 4; ++j) {
                const int d = dt*16 + lg*4 + j;
                if (d < HD) orow[d] = om[0][dt][j]*li[0] + om[1][dt][j]*li[1];
            }
    }
}

// ---------------------------------------------------------------------------
// out_small[b][o][n] = osum[b][n][:] . wf[:][o] + bf[o]
// z-split over 3 o-strips of 128: 768 blocks, 2 blocks/CU (was 256 @ 1/CU).
// ---------------------------------------------------------------------------
__global__ __launch_bounds__(256) void outgemm_kernel(
    const float* __restrict__ osum, const float* __restrict__ wf, const float* __restrict__ bf,
    float* __restrict__ outs)
{
    const int tid = threadIdx.x;
    const int n0 = blockIdx.x * 32;
    const int b  = blockIdx.y;
    const int o0 = blockIdx.z * 128;
    __shared__ float ax[32*97];
    __shared__ float lw[96*128];
    for (int e = tid; e < 32*96; e += 256) {
        const int n = e / 96, c = e - n*96;
        ax[n*97 + c] = osum[((size_t)b*Nn + n0 + n)*Cc + c];
    }
    for (int e = tid; e < 96*128; e += 256) {
        const int c = e >> 7, j = e & 127;
        lw[c*128 + j] = wf[(size_t)c*Dd + o0 + j];
    }
    __syncthreads();
    const int tn = (tid & 7) * 4;
    const int tj = (tid >> 3) * 4;
    float acc[4][4] = {};
    for (int c = 0; c < 96; ++c) {
        const float4 wv = *(const float4*)&lw[c*128 + tj];
        #pragma unroll
        for (int i = 0; i < 4; ++i) {
            const float a = ax[(tn+i)*97 + c];
            acc[i][0] = fmaf(a, wv.x, acc[i][0]);
            acc[i][1] = fmaf(a, wv.y, acc[i][1]);
            acc[i][2] = fmaf(a, wv.z, acc[i][2]);
            acc[i][3] = fmaf(a, wv.w, acc[i][3]);
        }
    }
    #pragma unroll
    for (int j = 0; j < 4; ++j) {
        const int o = o0 + tj + j;
        const float bb = bf[o];
        #pragma unroll
        for (int i = 0; i < 4; ++i)
            outs[((size_t)b*Dd + o)*Nn + n0 + tn + i] = acc[i][j] + bb;
    }
}

// ---------------------------------------------------------------------------
// Bilinear x4 upsample, align_corners=True: 32x32 -> 128x128 per (b,ch).
// ---------------------------------------------------------------------------
__global__ __launch_bounds__(256) void upsample_kernel(
    const float* __restrict__ src, float* __restrict__ dst)
{
    const int gid = blockIdx.x * 256 + threadIdx.x;
    const int ox4 = gid & 31;
    const int oy  = (gid >> 5) & 127;
    const int bc  = gid >> 12;
    const float* s = src + (size_t)bc * 1024;
    const float sy = oy * (31.0f / 127.0f);
    const int y0 = (int)sy;
    const int y1 = min(y0 + 1, 31);
    const float wy = sy - (float)y0;
    const float* r0 = s + y0 * 32;
    const float* r1 = s + y1 * 32;
    float res[4];
    #pragma unroll
    for (int j = 0; j < 4; ++j) {
        const int ox = ox4 * 4 + j;
        const float sx = ox * (31.0f / 127.0f);
        const int x0 = (int)sx;
        const int x1 = min(x0 + 1, 31);
        const float wx = sx - (float)x0;
        const float t0 = r0[x0] * (1.0f - wx) + r0[x1] * wx;
        const float t1 = r1[x0] * (1.0f - wx) + r1[x1] * wx;
        res[j] = t0 * (1.0f - wy) + t1 * wy;
    }
    *(float4*)(dst + (size_t)gid * 4) = make_float4(res[0], res[1], res[2], res[3]);
}

// ---------------------------------------------------------------------------
extern "C" void kernel_launch(void* const* d_in, const int* in_sizes, int n_in,
                              void* d_out, int out_size, void* d_ws, size_t ws_size,
                              hipStream_t stream)
{
    const float* x      = (const float*)d_in[0];
    const float* w_le   = (const float*)d_in[1];
    const float* b_le   = (const float*)d_in[2];
    const float* bn_le  = (const float*)d_in[3];
    const float* w_max  = (const float*)d_in[4];
    const float* b_max  = (const float*)d_in[5];
    const float* bn_max = (const float*)d_in[6];
    const float* w_avg  = (const float*)d_in[7];
    const float* b_avg  = (const float*)d_in[8];
    const float* bn_avg = (const float*)d_in[9];
    const float* btab   = (const float*)d_in[10];
    const float* w_q    = (const float*)d_in[11];
    const float* w_kv   = (const float*)d_in[12];
    const float* w_proj = (const float*)d_in[13];
    const float* b_proj = (const float*)d_in[14];
    const float* w_out  = (const float*)d_in[15];
    const float* b_out  = (const float*)d_in[16];
    (void)in_sizes; (void)n_in; (void)out_size; (void)ws_size;

    float* ws = (float*)d_ws;
    const size_t T  = (size_t)Bb * Cc * Nn;          // 786432 floats
    const size_t AS = (size_t)Bb * NH * Nn * 32;     // 1048576 u16 per bf16 array

    float* xq   = ws + 0*T;
    float* tmx  = ws + 1*T;
    float* tav  = ws + 2*T;
    u16*  bb16  = (u16*)(ws + 3*T);                  // 10 bf16 arrays, 20 MB
    u16* qh  = bb16 + 0*AS;  u16* ql  = bb16 + 1*AS;
    u16* k1h = bb16 + 2*AS;  u16* k1l = bb16 + 3*AS;
    u16* k2h = bb16 + 4*AS;  u16* k2l = bb16 + 5*AS;
    u16* v1h = bb16 + 6*AS;  u16* v1l = bb16 + 7*AS;
    u16* v2h = bb16 + 8*AS;  u16* v2l = bb16 + 9*AS;
    float* osum = (float*)(bb16 + 10*AS);
    float* wf   = osum + T;                          // 96*384
    float* bf   = wf + (size_t)Cc*Dd;                // 384
    float* btr  = bf + Dd;                           // 4*3969
    float* outs = ws;   // aliases [ws, ws+4T): stem bufs + qh/ql,
                        // all dead once outgemm runs (stream-serial)

    stem_kernel<<<dim3(4, 97, 8), 256, 0, stream>>>(
        x, w_le, b_le, bn_le, w_max, b_max, bn_max, w_avg, b_avg, bn_avg,
        w_proj, b_proj, w_out, b_out, btab, xq, tmx, tav, wf, bf, btr);
    proj_kernel<<<dim3(32, 8, 5), 256, 0, stream>>>(
        xq, tmx, tav, w_q, w_kv, qh, ql, k1h, k1l, k2h, k2l, v1h, v1l, v2h, v2l);
    attn_kernel<<<dim3(32, 4, 8), 256, 0, stream>>>(
        qh, ql, k1h, k1l, k2h, k2l, v1h, v1l, v2h, v2l, btr, osum);
    outgemm_kernel<<<dim3(32, 8, 3), 256, 0, stream>>>(osum, wf, bf, outs);
    upsample_kernel<<<dim3(49152), 256, 0, stream>>>(outs, (float*)d_out);
}

// Round 4
// 506.149 us; speedup vs baseline: 1.0786x; 1.0650x over previous
//
#include <hip/hip_runtime.h>
#include <math.h>

namespace {
constexpr int Bb  = 8;
constexpr int Dd  = 384;
constexpr int HIN = 128;
constexpr int Cc  = 96;
constexpr int Nn  = 1024;
constexpr int NH  = 4;
constexpr int HD  = 24;
}
#define BN_EPS 1e-5f
#define QSCALE 0.20412414523193154f  /* 24^-0.5 */

typedef unsigned short u16;
typedef unsigned int   u32;
typedef __attribute__((ext_vector_type(8))) short bh8;   // 8 bf16 = 4 VGPR (MFMA A/B frag)
typedef __attribute__((ext_vector_type(4))) float fx4;   // MFMA C/D frag

#define MFMA16(a,b,c) __builtin_amdgcn_mfma_f32_16x16x32_bf16((a),(b),(c),0,0,0)

union PackU { u32 u[4]; bh8 s; };

// truncated hi/lo bf16 split: v == hi + lo to ~2^-16 relative
__device__ __forceinline__ void split1(float v, u16& hi, u16& lo) {
    const u32 bv = __float_as_uint(v);
    const u32 hb = bv & 0xffff0000u;
    hi = (u16)(bv >> 16);
    const float r = v - __uint_as_float(hb);   // exact (same exponent)
    lo = (u16)(__float_as_uint(r) >> 16);
}
// pack two floats into one dword of 2 bf16 (x->lo half, y->hi half) + residual pack
__device__ __forceinline__ void split2(float x, float y, u32& hi, u32& lo) {
    const u32 bx = __float_as_uint(x), by = __float_as_uint(y);
    const u32 hx = bx & 0xffff0000u, hy = by & 0xffff0000u;
    hi = (hx >> 16) | hy;
    const float rx = x - __uint_as_float(hx);
    const float ry = y - __uint_as_float(hy);
    lo = (__float_as_uint(rx) >> 16) | (__float_as_uint(ry) & 0xffff0000u);
}

__device__ __forceinline__ float bn_relu6(float y, const float* __restrict__ bn, int c) {
    float gam = bn[c], bet = bn[Cc + c], mu = bn[2*Cc + c], var = bn[3*Cc + c];
    float s = gam / sqrtf(var + BN_EPS);
    float r = (y - mu) * s + bet;
    return fminf(fmaxf(r, 0.0f), 6.0f);
}

// ---------------------------------------------------------------------------
// Stem: fused (grouped 4x4/s4 conv | 4x4 maxpool+grouped1x1 | 4x4 avgpool+grouped1x1)
// Extra blocks (blockIdx.y == 96, 32 blocks): fusew (w_proj x w_out) + bias
// table transpose btr[h][3969] (so attn's LDS fill is coalesced).
// ---------------------------------------------------------------------------
__global__ __launch_bounds__(256) void stem_kernel(
    const float* __restrict__ x, const float* __restrict__ w_le,
    const float* __restrict__ b_le, const float* __restrict__ bn_le,
    const float* __restrict__ w_max, const float* __restrict__ b_max, const float* __restrict__ bn_max,
    const float* __restrict__ w_avg, const float* __restrict__ b_avg, const float* __restrict__ bn_avg,
    const float* __restrict__ w_proj, const float* __restrict__ b_proj,
    const float* __restrict__ w_out, const float* __restrict__ b_out,
    const float* __restrict__ btab,
    float* __restrict__ xq, float* __restrict__ tmx, float* __restrict__ tav,
    float* __restrict__ wf, float* __restrict__ bf, float* __restrict__ btr)
{
    const int tid = threadIdx.x;
    if (blockIdx.y == 96) {
        // ---- fused-weight + bias-transpose side work ----
        const int tg = (blockIdx.z*4 + blockIdx.x)*256 + tid;   // 0..8191
        for (int e = tg; e < Cc*Dd; e += 8192) {
            const int c = e / Dd, o = e - c*Dd;
            const float* wp = w_proj + c*Cc;
            const float* wo = w_out + (size_t)o*Cc;
            float acc = 0.0f;
            for (int c2 = 0; c2 < Cc; ++c2) acc = fmaf(wp[c2], wo[c2], acc);
            wf[e] = acc;
        }
        if (tg < Dd) {
            const float* wo = w_out + (size_t)tg*Cc;
            float acc = 0.0f;
            for (int c = 0; c < Cc; ++c) acc = fmaf(b_proj[c], wo[c], acc);
            bf[tg] = b_out[tg] + 2.0f * acc;
        }
        for (int e = tg; e < 3969*NH; e += 8192) {
            const int hh = e / 3969, i = e - hh*3969;
            btr[e] = btab[i*NH + hh];
        }
        return;
    }
    const int n = blockIdx.x * 256 + tid;
    const int g = blockIdx.y;
    const int b = blockIdx.z;
    const int oh = n >> 5, ow = n & 31;

    const float* xb = x + (((size_t)b * Dd + 4*g) * HIN + 4*oh) * HIN + 4*ow;
    float conv = 0.0f, mxv = 0.0f, avv = 0.0f;
    #pragma unroll
    for (int i = 0; i < 4; ++i) {
        float cmax = -3.0e38f, csum = 0.0f;
        #pragma unroll
        for (int kh = 0; kh < 4; ++kh) {
            const float4 v = *(const float4*)(xb + ((size_t)i * HIN + kh) * HIN);
            const float* wl = w_le + (((g*4 + i)*4 + kh) * 4);
            conv = fmaf(v.x, wl[0], conv);
            conv = fmaf(v.y, wl[1], conv);
            conv = fmaf(v.z, wl[2], conv);
            conv = fmaf(v.w, wl[3], conv);
            cmax = fmaxf(cmax, fmaxf(fmaxf(v.x, v.y), fmaxf(v.z, v.w)));
            csum += (v.x + v.y) + (v.z + v.w);
        }
        mxv = fmaf(cmax, w_max[g*4 + i], mxv);
        avv = fmaf(csum * (1.0f/16.0f), w_avg[g*4 + i], avv);
    }
    const float xqv = bn_relu6(conv + b_le[g], bn_le, g);
    const float tm  = bn_relu6(mxv  + b_max[g], bn_max, g);
    const float ta  = bn_relu6(avv  + b_avg[g], bn_avg, g);
    const size_t o = ((size_t)b * Cc + g) * Nn + n;
    xq[o] = xqv; tmx[o] = tm; tav[o] = ta;
}

// ---------------------------------------------------------------------------
// Projections -> bf16 hi/lo MFMA operand layouts. 5-way phase split
// (z = {q, k1, k2, v1, v2}).
//   Q:  [bh][n][32]  (d pad 24..31 = 0; QSCALE pre-applied)
//   K:  [bh][rho(n)][32]  rows permuted within each 32-chunk (PV slot match)
//   V^T:[bh][32][n]  (d rows 24..31 = 0)
// ---------------------------------------------------------------------------
__global__ __launch_bounds__(256, 3) void proj_kernel(
    const float* __restrict__ xq, const float* __restrict__ tmx, const float* __restrict__ tav,
    const float* __restrict__ w_q, const float* __restrict__ w_kv,
    u16* __restrict__ qhp, u16* __restrict__ qlp,
    u16* __restrict__ k1h, u16* __restrict__ k1l, u16* __restrict__ k2h, u16* __restrict__ k2l,
    u16* __restrict__ v1h, u16* __restrict__ v1l, u16* __restrict__ v2h, u16* __restrict__ v2l)
{
    const int tid   = threadIdx.x;
    const int n0    = blockIdx.x * 32;
    const int b     = blockIdx.y;
    const int phase = blockIdx.z;          // 0=q 1=k1 2=k2 3=v1 4=v2
    __shared__ float A[32*97];
    __shared__ float lw[96*96];

    const float* asrc = (phase == 0) ? xq : ((phase == 1 || phase == 3) ? tmx : tav);
    for (int e = tid; e < 96*32; e += 256) {
        const int c = e >> 5, j = e & 31;
        A[j*97 + c] = asrc[((size_t)b * Cc + c) * Nn + n0 + j];
    }
    const float* wsrc = (phase == 0) ? w_q : w_kv;
    const int RS = (phase == 0) ? 96 : 192;
    const int WO = (phase <= 2) ? 0 : 96;
    for (int e = tid; e < 96*96; e += 256)
        lw[e] = wsrc[(e/96)*RS + WO + (e%96)];
    __syncthreads();

    const int tn = (tid & 7) * 4;   // 4 rows (n)
    const int tc = (tid >> 3) * 3;  // 3 cols

    float acc[4][3] = {};
    for (int k = 0; k < 96; ++k) {
        const float w0 = lw[k*96 + tc + 0];
        const float w1 = lw[k*96 + tc + 1];
        const float w2 = lw[k*96 + tc + 2];
        #pragma unroll
        for (int i = 0; i < 4; ++i) {
            const float a = A[(tn+i)*97 + k];
            acc[i][0] = fmaf(a, w0, acc[i][0]);
            acc[i][1] = fmaf(a, w1, acc[i][1]);
            acc[i][2] = fmaf(a, w2, acc[i][2]);
        }
    }

    u16* dh; u16* dl;
    if      (phase == 0) { dh = qhp; dl = qlp; }
    else if (phase == 1) { dh = k1h; dl = k1l; }
    else if (phase == 2) { dh = k2h; dl = k2l; }
    else if (phase == 3) { dh = v1h; dl = v1l; }
    else                 { dh = v2h; dl = v2l; }

    #pragma unroll
    for (int j = 0; j < 3; ++j) {
        const int col = tc + j, hh = col / HD, d = col - hh*HD;
        #pragma unroll
        for (int i = 0; i < 4; ++i) {
            const int n = n0 + tn + i;
            float v = acc[i][j];
            size_t dst;
            if (phase == 0) {
                v *= QSCALE;
                dst = ((size_t)(b*NH + hh)*Nn + n)*32 + d;
            } else if (phase <= 2) {
                const int rho = (n & ~31) | ((n & 4) << 2) | ((n & 24) >> 1) | (n & 3);
                dst = ((size_t)(b*NH + hh)*Nn + rho)*32 + d;
            } else {
                dst = ((size_t)(b*NH + hh)*32 + d)*Nn + n;
            }
            u16 hi, lo;
            split1(v, hi, lo);
            dh[dst] = hi; dl[dst] = lo;
        }
    }

    // pad zeroing (d = 24..31 must be finite-zero: 0*NaN hazard)
    for (int e = tid; e < 1024; e += 256) {
        const int hh = e >> 8;
        const int nn = (e >> 3) & 31;
        const int d  = 24 + (e & 7);
        const int n  = n0 + nn;
        const size_t dst = (phase <= 2)
            ? ((size_t)(b*NH + hh)*Nn + n)*32 + d
            : ((size_t)(b*NH + hh)*32 + d)*Nn + n;
        dh[dst] = 0; dl[dst] = 0;
    }
}

// ---------------------------------------------------------------------------
// MFMA flash attention. 1 wave per block = 32 queries (2 q-groups) x 1024
// keys x ONE branch (branches in grid.z; their normalized outputs are
// independent and summed later -- linearity through w_fused). Each K/V
// fragment load feeds 6 MFMAs (2 q-groups): 2x arithmetic intensity, half
// total K/V traffic vs the ks-split version. No in-loop syncs, no merge.
// Defer-max (THR=8): m updated only under wave-uniform __all with the
// lg-reduced tmax, so the 4 lanes of one query always share m.
// ---------------------------------------------------------------------------
__global__ __launch_bounds__(64) void attn_kernel(
    const u16* __restrict__ qhp, const u16* __restrict__ qlp,
    const u16* __restrict__ k1h, const u16* __restrict__ k1l,
    const u16* __restrict__ k2h, const u16* __restrict__ k2l,
    const u16* __restrict__ v1h, const u16* __restrict__ v1l,
    const u16* __restrict__ v2h, const u16* __restrict__ v2l,
    const float* __restrict__ btr,
    float* __restrict__ osum1, float* __restrict__ osum2)
{
    const int tid = threadIdx.x;       // 0..63, one wave
    const int h  = blockIdx.y;
    const int b  = blockIdx.z >> 1;
    const int br = blockIdx.z & 1;
    const int bh = b*NH + h;

    __shared__ float biasl[3969];
    for (int e = tid; e < 3969; e += 64) biasl[e] = btr[h*3969 + e];
    __syncthreads();

    const int lg = tid >> 4;     // lane group 0..3
    const int lr = tid & 15;
    const int q0 = blockIdx.x * 32;
    const int qA = q0 + lr;            // query group A
    const int yn = q0 >> 5;            // shared by both groups (q0 % 32 == 0)

    const u16* kh = br ? k2h : k1h;
    const u16* kl = br ? k2l : k1l;
    const u16* vh = br ? v2h : v1h;
    const u16* vl = br ? v2l : v1l;
    float* osb    = br ? osum2 : osum1;

    const size_t qoff = ((size_t)bh*Nn + qA)*32 + lg*8;
    const bh8 qAh = *(const bh8*)(qhp + qoff);
    const bh8 qAl = *(const bh8*)(qlp + qoff);
    const bh8 qBh = *(const bh8*)(qhp + qoff + 512);   // +16 queries
    const bh8 qBl = *(const bh8*)(qlp + qoff + 512);

    kh += ((size_t)bh*Nn + lr)*32 + lg*8;
    kl += ((size_t)bh*Nn + lr)*32 + lg*8;
    vh += ((size_t)bh*32 + lr)*Nn + lg*8;
    vl += ((size_t)bh*32 + lr)*Nn + lg*8;

    const fx4 zero = {0.0f, 0.0f, 0.0f, 0.0f};
    fx4 oA[2] = {zero, zero}, oB[2] = {zero, zero};
    float mA = -3.0e38f, mB = -3.0e38f, lA = 0.0f, lB = 0.0f;

    for (int it = 0; it < 16; ++it) {
        const int kb = it*64;
        fx4 sA[4], sB[4];
        #pragma unroll
        for (int t = 0; t < 4; ++t) {
            const int ro = (kb + t*16)*32;
            const bh8 ah = *(const bh8*)(kh + ro);
            const bh8 al = *(const bh8*)(kl + ro);
            // actual key of C elem (t, lg, j): kb + 32*(t>>1) + 4*(t&1) + 8*lg + j
            const int ym   = (kb >> 5) + (t >> 1);
            const int xmb  = (t & 1)*4 + lg*8;
            const int rowb = (yn - ym + 31)*63 + (lr + 31) - xmb;
            fx4 uA, uB;
            #pragma unroll
            for (int j = 0; j < 4; ++j) {
                uA[j] = biasl[rowb - j];
                uB[j] = biasl[rowb + 16 - j];
            }
            uA = MFMA16(ah, qAh, uA);
            uA = MFMA16(ah, qAl, uA);
            uA = MFMA16(al, qAh, uA);
            uB = MFMA16(ah, qBh, uB);
            uB = MFMA16(ah, qBl, uB);
            uB = MFMA16(al, qBh, uB);
            sA[t] = uA; sB[t] = uB;
        }

        // lane-local maxima
        float lmA = fmaxf(fmaxf(sA[0][0], sA[0][1]), fmaxf(sA[0][2], sA[0][3]));
        float lmB = fmaxf(fmaxf(sB[0][0], sB[0][1]), fmaxf(sB[0][2], sB[0][3]));
        #pragma unroll
        for (int t = 1; t < 4; ++t) {
            lmA = fmaxf(lmA, fmaxf(fmaxf(sA[t][0], sA[t][1]), fmaxf(sA[t][2], sA[t][3])));
            lmB = fmaxf(lmB, fmaxf(fmaxf(sB[t][0], sB[t][1]), fmaxf(sB[t][2], sB[t][3])));
        }
        // T13 defer-max: rescale only when some lane grows past m + 8
        if (!__all(lmA <= mA + 8.0f)) {
            float tmax = lmA;
            tmax = fmaxf(tmax, __shfl_xor(tmax, 16));
            tmax = fmaxf(tmax, __shfl_xor(tmax, 32));
            const float M = fmaxf(mA, tmax);
            const float c = __expf(mA - M);
            lA *= c; oA[0] *= c; oA[1] *= c;
            mA = M;
        }
        if (!__all(lmB <= mB + 8.0f)) {
            float tmax = lmB;
            tmax = fmaxf(tmax, __shfl_xor(tmax, 16));
            tmax = fmaxf(tmax, __shfl_xor(tmax, 32));
            const float M = fmaxf(mB, tmax);
            const float c = __expf(mB - M);
            lB *= c; oB[0] *= c; oB[1] *= c;
            mB = M;
        }

        #pragma unroll
        for (int ch = 0; ch < 2; ++ch) {
            const float a0 = __expf(sA[2*ch  ][0] - mA);
            const float a1 = __expf(sA[2*ch  ][1] - mA);
            const float a2 = __expf(sA[2*ch  ][2] - mA);
            const float a3 = __expf(sA[2*ch  ][3] - mA);
            const float a4 = __expf(sA[2*ch+1][0] - mA);
            const float a5 = __expf(sA[2*ch+1][1] - mA);
            const float a6 = __expf(sA[2*ch+1][2] - mA);
            const float a7 = __expf(sA[2*ch+1][3] - mA);
            lA += ((a0 + a1) + (a2 + a3)) + ((a4 + a5) + (a6 + a7));
            const float b0 = __expf(sB[2*ch  ][0] - mB);
            const float b1 = __expf(sB[2*ch  ][1] - mB);
            const float b2 = __expf(sB[2*ch  ][2] - mB);
            const float b3 = __expf(sB[2*ch  ][3] - mB);
            const float b4 = __expf(sB[2*ch+1][0] - mB);
            const float b5 = __expf(sB[2*ch+1][1] - mB);
            const float b6 = __expf(sB[2*ch+1][2] - mB);
            const float b7 = __expf(sB[2*ch+1][3] - mB);
            lB += ((b0 + b1) + (b2 + b3)) + ((b4 + b5) + (b6 + b7));

            PackU pAh, pAl, pBh, pBl;
            split2(a0, a1, pAh.u[0], pAl.u[0]);
            split2(a2, a3, pAh.u[1], pAl.u[1]);
            split2(a4, a5, pAh.u[2], pAl.u[2]);
            split2(a6, a7, pAh.u[3], pAl.u[3]);
            split2(b0, b1, pBh.u[0], pBl.u[0]);
            split2(b2, b3, pBh.u[1], pBl.u[1]);
            split2(b4, b5, pBh.u[2], pBl.u[2]);
            split2(b6, b7, pBh.u[3], pBl.u[3]);

            const int vo0 = kb + ch*32;
            #pragma unroll
            for (int dt = 0; dt < 2; ++dt) {
                const size_t vo = (size_t)(dt*16)*Nn + vo0;
                const bh8 wh_ = *(const bh8*)(vh + vo);
                const bh8 wl_ = *(const bh8*)(vl + vo);
                oA[dt] = MFMA16(wh_, pAh.s, oA[dt]);
                oA[dt] = MFMA16(wh_, pAl.s, oA[dt]);
                oA[dt] = MFMA16(wl_, pAh.s, oA[dt]);
                oB[dt] = MFMA16(wh_, pBh.s, oB[dt]);
                oB[dt] = MFMA16(wh_, pBl.s, oB[dt]);
                oB[dt] = MFMA16(wl_, pBh.s, oB[dt]);
            }
        }
    }

    lA += __shfl_xor(lA, 16); lA += __shfl_xor(lA, 32);
    lB += __shfl_xor(lB, 16); lB += __shfl_xor(lB, 32);
    const float iA = 1.0f / lA, iB = 1.0f / lB;
    float* orowA = osb + ((size_t)b*Nn + qA)*Cc + h*HD;
    float* orowB = orowA + 16*Cc;
    #pragma unroll
    for (int dt = 0; dt < 2; ++dt)
        #pragma unroll
        for (int j = 0; j < 4; ++j) {
            const int d = dt*16 + lg*4 + j;
            if (d < HD) {
                orowA[d] = oA[dt][j]*iA;
                orowB[d] = oB[dt][j]*iB;
            }
        }
}

// ---------------------------------------------------------------------------
// out_small[b][o][n] = (osum1+osum2)[b][n][:] . wf[:][o] + bf[o]
// z-split over 3 o-strips of 128.
// ---------------------------------------------------------------------------
__global__ __launch_bounds__(256) void outgemm_kernel(
    const float* __restrict__ osum1, const float* __restrict__ osum2,
    const float* __restrict__ wf, const float* __restrict__ bf,
    float* __restrict__ outs)
{
    const int tid = threadIdx.x;
    const int n0 = blockIdx.x * 32;
    const int b  = blockIdx.y;
    const int o0 = blockIdx.z * 128;
    __shared__ float ax[32*97];
    __shared__ float lw[96*128];
    for (int e = tid; e < 32*96; e += 256) {
        const int n = e / 96, c = e - n*96;
        const size_t src = ((size_t)b*Nn + n0 + n)*Cc + c;
        ax[n*97 + c] = osum1[src] + osum2[src];
    }
    for (int e = tid; e < 96*128; e += 256) {
        const int c = e >> 7, j = e & 127;
        lw[c*128 + j] = wf[(size_t)c*Dd + o0 + j];
    }
    __syncthreads();
    const int tn = (tid & 7) * 4;
    const int tj = (tid >> 3) * 4;
    float acc[4][4] = {};
    for (int c = 0; c < 96; ++c) {
        const float4 wv = *(const float4*)&lw[c*128 + tj];
        #pragma unroll
        for (int i = 0; i < 4; ++i) {
            const float a = ax[(tn+i)*97 + c];
            acc[i][0] = fmaf(a, wv.x, acc[i][0]);
            acc[i][1] = fmaf(a, wv.y, acc[i][1]);
            acc[i][2] = fmaf(a, wv.z, acc[i][2]);
            acc[i][3] = fmaf(a, wv.w, acc[i][3]);
        }
    }
    #pragma unroll
    for (int j = 0; j < 4; ++j) {
        const int o = o0 + tj + j;
        const float bb = bf[o];
        #pragma unroll
        for (int i = 0; i < 4; ++i)
            outs[((size_t)b*Dd + o)*Nn + n0 + tn + i] = acc[i][j] + bb;
    }
}

// ---------------------------------------------------------------------------
// Bilinear x4 upsample, align_corners=True: 32x32 -> 128x128 per (b,ch).
// ---------------------------------------------------------------------------
__global__ __launch_bounds__(256) void upsample_kernel(
    const float* __restrict__ src, float* __restrict__ dst)
{
    const int gid = blockIdx.x * 256 + threadIdx.x;
    const int ox4 = gid & 31;
    const int oy  = (gid >> 5) & 127;
    const int bc  = gid >> 12;
    const float* s = src + (size_t)bc * 1024;
    const float sy = oy * (31.0f / 127.0f);
    const int y0 = (int)sy;
    const int y1 = min(y0 + 1, 31);
    const float wy = sy - (float)y0;
    const float* r0 = s + y0 * 32;
    const float* r1 = s + y1 * 32;
    float res[4];
    #pragma unroll
    for (int j = 0; j < 4; ++j) {
        const int ox = ox4 * 4 + j;
        const float sx = ox * (31.0f / 127.0f);
        const int x0 = (int)sx;
        const int x1 = min(x0 + 1, 31);
        const float wx = sx - (float)x0;
        const float t0 = r0[x0] * (1.0f - wx) + r0[x1] * wx;
        const float t1 = r1[x0] * (1.0f - wx) + r1[x1] * wx;
        res[j] = t0 * (1.0f - wy) + t1 * wy;
    }
    *(float4*)(dst + (size_t)gid * 4) = make_float4(res[0], res[1], res[2], res[3]);
}

// ---------------------------------------------------------------------------
extern "C" void kernel_launch(void* const* d_in, const int* in_sizes, int n_in,
                              void* d_out, int out_size, void* d_ws, size_t ws_size,
                              hipStream_t stream)
{
    const float* x      = (const float*)d_in[0];
    const float* w_le   = (const float*)d_in[1];
    const float* b_le   = (const float*)d_in[2];
    const float* bn_le  = (const float*)d_in[3];
    const float* w_max  = (const float*)d_in[4];
    const float* b_max  = (const float*)d_in[5];
    const float* bn_max = (const float*)d_in[6];
    const float* w_avg  = (const float*)d_in[7];
    const float* b_avg  = (const float*)d_in[8];
    const float* bn_avg = (const float*)d_in[9];
    const float* btab   = (const float*)d_in[10];
    const float* w_q    = (const float*)d_in[11];
    const float* w_kv   = (const float*)d_in[12];
    const float* w_proj = (const float*)d_in[13];
    const float* b_proj = (const float*)d_in[14];
    const float* w_out  = (const float*)d_in[15];
    const float* b_out  = (const float*)d_in[16];
    (void)in_sizes; (void)n_in; (void)out_size; (void)ws_size;

    float* ws = (float*)d_ws;
    const size_t T  = (size_t)Bb * Cc * Nn;          // 786432 floats
    const size_t AS = (size_t)Bb * NH * Nn * 32;     // 1048576 u16 per bf16 array

    float* xq   = ws + 0*T;
    float* tmx  = ws + 1*T;
    float* tav  = ws + 2*T;
    u16*  bb16  = (u16*)(ws + 3*T);                  // 10 bf16 arrays, 20 MB
    u16* qh  = bb16 + 0*AS;  u16* ql  = bb16 + 1*AS;
    u16* k1h = bb16 + 2*AS;  u16* k1l = bb16 + 3*AS;
    u16* k2h = bb16 + 4*AS;  u16* k2l = bb16 + 5*AS;
    u16* v1h = bb16 + 6*AS;  u16* v1l = bb16 + 7*AS;
    u16* v2h = bb16 + 8*AS;  u16* v2l = bb16 + 9*AS;
    float* osum1 = (float*)(bb16 + 10*AS);
    float* wf    = osum1 + T;                        // 96*384
    float* bf    = wf + (size_t)Cc*Dd;               // 384
    float* btr   = bf + Dd;                          // 4*3969
    float* osum2 = btr + 4*3969;
    float* outs  = ws;  // aliases [ws, ws+4T): stem bufs + qh/ql,
                        // all dead once outgemm runs (stream-serial)

    stem_kernel<<<dim3(4, 97, 8), 256, 0, stream>>>(
        x, w_le, b_le, bn_le, w_max, b_max, bn_max, w_avg, b_avg, bn_avg,
        w_proj, b_proj, w_out, b_out, btab, xq, tmx, tav, wf, bf, btr);
    proj_kernel<<<dim3(32, 8, 5), 256, 0, stream>>>(
        xq, tmx, tav, w_q, w_kv, qh, ql, k1h, k1l, k2h, k2l, v1h, v1l, v2h, v2l);
    attn_kernel<<<dim3(32, 4, 16), 64, 0, stream>>>(
        qh, ql, k1h, k1l, k2h, k2l, v1h, v1l, v2h, v2l, btr, osum1, osum2);
    outgemm_kernel<<<dim3(32, 8, 3), 256, 0, stream>>>(osum1, osum2, wf, bf, outs);
    upsample_kernel<<<dim3(49152), 256, 0, stream>>>(outs, (float*)d_out);
}